// Round 3
// baseline (24.194 us; speedup 1.0000x reference)
//
#include <hip/hip_runtime.h>

// YOLO head decode: x [bs, nm*attrs, H, W] fp32, anchors [nm,2] fp32
// out = concat(pred [bs,nm,H,W,7], valid [bs,nm,H,W]) fp32 (valid as 0/1)
//
// R3: same per-thread work as R2 (1 elem/thread, scalar dword loads over
// 85 planes) but block 256 -> 1024. Each (block, plane) stream granule
// grows 1KB -> 4KB contiguous, 4x better DRAM page locality, while
// occupancy stays ~17 waves/CU (271 blocks x 16 waves, all resident).

#define BS    16
#define NM    3
#define NC    80
#define ATTRS (5 + NC)
#define HH    76
#define WW    76
#define HWSZ  (HH * WW)
#define VAL_CONF 0.1f

__device__ __forceinline__ float sigmoidf(float v) {
    return 1.0f / (1.0f + __expf(-v));
}

__global__ __launch_bounds__(1024) void yolo_head_kernel(
    const float* __restrict__ x,
    const float* __restrict__ anchors,
    float* __restrict__ out) {

    const int tid = blockIdx.x * blockDim.x + threadIdx.x;
    if (tid >= BS * NM * HWSZ) return;

    const int bm = tid / HWSZ;          // (batch, mask) plane group
    const int hw = tid - bm * HWSZ;
    const int m  = bm % NM;

    const float aw = anchors[2 * m + 0];
    const float ah = anchors[2 * m + 1];

    const float* base = x + (size_t)bm * ATTRS * HWSZ + hw;

    const float tx = base[0 * HWSZ];
    const float ty = base[1 * HWSZ];
    const float tw = base[2 * HWSZ];
    const float th = base[3 * HWSZ];
    const float tc = base[4 * HWSZ];

    // class max / argmax over RAW logits (sigmoid is monotonic);
    // strict > keeps first-max index, matching jnp.argmax.
    float mx = base[5 * HWSZ];
    int   mi = 0;
    #pragma unroll
    for (int k = 1; k < NC; ++k) {
        const float c = base[(size_t)(5 + k) * HWSZ];
        if (c > mx) { mx = c; mi = k; }
    }

    const int h = hw / WW;
    const int w = hw - h * WW;

    const float sx = sigmoidf(tx);
    const float sy = sigmoidf(ty);
    const float cx = (sx + (float)w) * (1.0f / (float)WW);
    const float cy = (sy + (float)h) * (1.0f / (float)HH);
    const float bw = __expf(tw) * aw;
    const float bh = __expf(th) * ah;
    const float conf      = sigmoidf(tc);
    const float cls_score = sigmoidf(mx);
    const float cls_idx   = (float)mi;

    const float fm = (conf > VAL_CONF) ? 1.0f : 0.0f;

    float* pred = out + (size_t)tid * 7;
    pred[0] = (cx - bw * 0.5f) * fm;
    pred[1] = (cy - bh * 0.5f) * fm;
    pred[2] = (cx + bw * 0.5f) * fm;
    pred[3] = (cy + bh * 0.5f) * fm;
    pred[4] = conf * fm;
    pred[5] = cls_score * fm;
    pred[6] = cls_idx * fm;

    out[(size_t)BS * NM * HWSZ * 7 + tid] = fm;
}

extern "C" void kernel_launch(void* const* d_in, const int* in_sizes, int n_in,
                              void* d_out, int out_size, void* d_ws, size_t ws_size,
                              hipStream_t stream) {
    const float* x       = (const float*)d_in[0];
    const float* anchors = (const float*)d_in[1];
    float* out           = (float*)d_out;

    const int total = BS * NM * HWSZ;            // 277,248
    const int block = 1024;
    const int grid  = (total + block - 1) / block;  // 271

    yolo_head_kernel<<<grid, block, 0, stream>>>(x, anchors, out);
}

// Round 4
// 22.629 us; speedup vs baseline: 1.0692x; 1.0692x over previous
//
#include <hip/hip_runtime.h>

// YOLO head decode: x [bs, nm*attrs, H, W] fp32, anchors [nm,2] fp32
// out = concat(pred [bs,nm,H,W,7], valid [bs,nm,H,W]) fp32 (valid as 0/1)
//
// R4: cooperative quad. 4 consecutive threads handle 4 consecutive
// locations. Class planes (80 of 85 = 94% of bytes) are loaded as float4
// split across the quad (20 planes/thread), combined via 2x shfl_xor with
// jnp.argmax first-max tie-break. Attrs+conf stay scalar per-location.
// 25 VMEM instrs/thread (vs 85 in R2), class loads 1KB/wave-instr, same
// occupancy as R2 (277,248 threads, 1083 x 256, ~17 waves/CU).

#define BS    16
#define NM    3
#define NC    80
#define ATTRS (5 + NC)
#define HH    76
#define WW    76
#define HWSZ  (HH * WW)
#define VAL_CONF 0.1f

typedef float f4 __attribute__((ext_vector_type(4)));

__device__ __forceinline__ float sigmoidf(float v) {
    return 1.0f / (1.0f + __expf(-v));
}

__global__ __launch_bounds__(256) void yolo_head_kernel(
    const float* __restrict__ x,
    const float* __restrict__ anchors,
    float* __restrict__ out) {

    const int gtid = blockIdx.x * blockDim.x + threadIdx.x;  // == location id
    const int t    = gtid & 3;        // slot within quad
    const int e0   = gtid & ~3;       // quad's first location (HWSZ%4==0 -> same bm)

    const int bm  = e0 / HWSZ;
    const int hw0 = e0 - bm * HWSZ;
    const int m   = bm % NM;

    const float aw = anchors[2 * m + 0];
    const float ah = anchors[2 * m + 1];

    const float* base = x + (size_t)bm * (ATTRS * HWSZ) + hw0;

    // --- per-location scalar attr loads (5 planes, 6% of bytes) ---
    const float tx = base[0 * HWSZ + t];
    const float ty = base[1 * HWSZ + t];
    const float tw = base[2 * HWSZ + t];
    const float th = base[3 * HWSZ + t];
    const float tc = base[4 * HWSZ + t];

    // --- cooperative class argmax over RAW logits (sigmoid monotonic) ---
    // thread t owns planes 5+t, 5+t+4, ... : 20 float4 loads covering the
    // quad's 4 locations. Strict > within thread (ascending k) keeps the
    // lowest index on ties, matching jnp.argmax.
    f4  mx = *(const f4*)(base + (size_t)(5 + t) * HWSZ);
    int mi[4] = {t, t, t, t};

    #pragma unroll
    for (int i = 1; i < NC / 4; ++i) {
        const int k = t + 4 * i;
        const f4 c = *(const f4*)(base + (size_t)(5 + k) * HWSZ);
        #pragma unroll
        for (int j = 0; j < 4; ++j) {
            if (c[j] > mx[j]) { mx[j] = c[j]; mi[j] = k; }
        }
    }

    // combine across the quad (xor 1, xor 2); lower class index wins ties
    #pragma unroll
    for (int d = 1; d <= 2; d <<= 1) {
        #pragma unroll
        for (int j = 0; j < 4; ++j) {
            const float omx = __shfl_xor(mx[j], d);
            const int   omi = __shfl_xor(mi[j], d);
            if (omx > mx[j] || (omx == mx[j] && omi < mi[j])) {
                mx[j] = omx; mi[j] = omi;
            }
        }
    }

    // my location's component (static select chain, no runtime indexing)
    const float mxv = (t == 0) ? mx[0] : (t == 1) ? mx[1] : (t == 2) ? mx[2] : mx[3];
    const int   miv = (t == 0) ? mi[0] : (t == 1) ? mi[1] : (t == 2) ? mi[2] : mi[3];

    // --- decode ---
    const int hw = hw0 + t;
    const int h  = hw / WW;
    const int w  = hw - h * WW;

    const float sx = sigmoidf(tx);
    const float sy = sigmoidf(ty);
    const float cx = (sx + (float)w) * (1.0f / (float)WW);
    const float cy = (sy + (float)h) * (1.0f / (float)HH);
    const float bw = __expf(tw) * aw;
    const float bh = __expf(th) * ah;
    const float conf      = sigmoidf(tc);
    const float cls_score = sigmoidf(mxv);
    const float cls_idx   = (float)miv;

    const float fm = (conf > VAL_CONF) ? 1.0f : 0.0f;

    float* pred = out + (size_t)gtid * 7;
    pred[0] = (cx - bw * 0.5f) * fm;
    pred[1] = (cy - bh * 0.5f) * fm;
    pred[2] = (cx + bw * 0.5f) * fm;
    pred[3] = (cy + bh * 0.5f) * fm;
    pred[4] = conf * fm;
    pred[5] = cls_score * fm;
    pred[6] = cls_idx * fm;

    out[(size_t)BS * NM * HWSZ * 7 + gtid] = fm;
}

extern "C" void kernel_launch(void* const* d_in, const int* in_sizes, int n_in,
                              void* d_out, int out_size, void* d_ws, size_t ws_size,
                              hipStream_t stream) {
    const float* x       = (const float*)d_in[0];
    const float* anchors = (const float*)d_in[1];
    float* out           = (float*)d_out;

    const int total = BS * NM * HWSZ;        // 277,248
    const int block = 256;
    const int grid  = total / block;         // 1083 exactly

    yolo_head_kernel<<<grid, block, 0, stream>>>(x, anchors, out);
}

// Round 5
// 21.813 us; speedup vs baseline: 1.1092x; 1.0374x over previous
//
#include <hip/hip_runtime.h>

// YOLO head decode: x [bs, nm*attrs, H, W] fp32, anchors [nm,2] fp32
// out = concat(pred [bs,nm,H,W,7], valid [bs,nm,H,W]) fp32 (valid as 0/1)
//
// R5: revert to R2 structure (best measured: 21.95us) — 1 location/thread,
// 85 scalar dword loads, 1083 x 256 grid (~17 waves/CU, no tail).
// Micro-fix: class argmax split into two independent even/odd chains to
// halve the serial compare-select dependency (merged with index tie-break
// preserving jnp.argmax first-max semantics).
//
// Structural floor: all 94.3 MB of input feeds the output (80 class planes
// for max/argmax + 5 attr planes), 8.9 MB written. 103 MB @ 6.3 TB/s
// achievable = 16.4 us; measured 22 = kernel ~17 us + graph/launch overhead.
// R2(scalar)/R3(1024-block)/R4(quad-float4) = 22.0/24.2/22.6 -> memory
// system saturated regardless of load width/occupancy quadrant.

#define BS    16
#define NM    3
#define NC    80
#define ATTRS (5 + NC)
#define HH    76
#define WW    76
#define HWSZ  (HH * WW)
#define VAL_CONF 0.1f

__device__ __forceinline__ float sigmoidf(float v) {
    return 1.0f / (1.0f + __expf(-v));
}

__global__ __launch_bounds__(256) void yolo_head_kernel(
    const float* __restrict__ x,
    const float* __restrict__ anchors,
    float* __restrict__ out) {

    const int tid = blockIdx.x * blockDim.x + threadIdx.x;   // location id

    const int bm = tid / HWSZ;          // (batch, mask) plane group
    const int hw = tid - bm * HWSZ;
    const int m  = bm % NM;

    const float aw = anchors[2 * m + 0];
    const float ah = anchors[2 * m + 1];

    const float* base = x + (size_t)bm * ATTRS * HWSZ + hw;

    const float tx = base[0 * HWSZ];
    const float ty = base[1 * HWSZ];
    const float tw = base[2 * HWSZ];
    const float th = base[3 * HWSZ];
    const float tc = base[4 * HWSZ];

    // class max / argmax over RAW logits (sigmoid is monotonic).
    // Two independent chains (even/odd k) halve the serial compare-select
    // latency; strict > within each ascending chain keeps lowest index,
    // cross-chain tie-break picks the smaller index -> jnp.argmax semantics.
    float mxa = base[(size_t)(5 + 0) * HWSZ];
    int   mia = 0;
    float mxb = base[(size_t)(5 + 1) * HWSZ];
    int   mib = 1;
    #pragma unroll
    for (int k = 2; k < NC; k += 2) {
        const float ca = base[(size_t)(5 + k) * HWSZ];
        const float cb = base[(size_t)(5 + k + 1) * HWSZ];
        if (ca > mxa) { mxa = ca; mia = k; }
        if (cb > mxb) { mxb = cb; mib = k + 1; }
    }
    float mx = mxa;
    int   mi = mia;
    if (mxb > mx || (mxb == mx && mib < mi)) { mx = mxb; mi = mib; }

    const int h = hw / WW;
    const int w = hw - h * WW;

    const float sx = sigmoidf(tx);
    const float sy = sigmoidf(ty);
    const float cx = (sx + (float)w) * (1.0f / (float)WW);
    const float cy = (sy + (float)h) * (1.0f / (float)HH);
    const float bw = __expf(tw) * aw;
    const float bh = __expf(th) * ah;
    const float conf      = sigmoidf(tc);
    const float cls_score = sigmoidf(mx);
    const float cls_idx   = (float)mi;

    const float fm = (conf > VAL_CONF) ? 1.0f : 0.0f;

    float* pred = out + (size_t)tid * 7;
    pred[0] = (cx - bw * 0.5f) * fm;
    pred[1] = (cy - bh * 0.5f) * fm;
    pred[2] = (cx + bw * 0.5f) * fm;
    pred[3] = (cy + bh * 0.5f) * fm;
    pred[4] = conf * fm;
    pred[5] = cls_score * fm;
    pred[6] = cls_idx * fm;

    out[(size_t)BS * NM * HWSZ * 7 + tid] = fm;
}

extern "C" void kernel_launch(void* const* d_in, const int* in_sizes, int n_in,
                              void* d_out, int out_size, void* d_ws, size_t ws_size,
                              hipStream_t stream) {
    const float* x       = (const float*)d_in[0];
    const float* anchors = (const float*)d_in[1];
    float* out           = (float*)d_out;

    const int total = BS * NM * HWSZ;        // 277,248
    const int block = 256;
    const int grid  = total / block;         // 1083 exactly, no tail

    yolo_head_kernel<<<grid, block, 0, stream>>>(x, anchors, out);
}